// Round 2
// baseline (297.214 us; speedup 1.0000x reference)
//
#include <hip/hip_runtime.h>
#include <math.h>

#define NCLS 19
#define NBATCH 4
#define HH 512
#define WW 512
#define PHD 129
#define PWD 129
#define PP (PHD*PWD)          // 16641
#define NC (NBATCH*NCLS)      // 76
#define KPOS 16129.0          // 127*127
#define NSTRIP 16             // i-strips of 8 rows (+2 halo)
#define GS 361                // gram stride per (n,c): full 19x19, upper triangle used
#define POS_ALPHA 5e-4

// ---------------------------------------------------------------------------
// Kernel 1: fused BCE + valid-count + avg-pool(4,4,pad2) of probs and onehot.
// One thread per pooled cell (n,c,ph,pw); pooled windows partition the input.
// Fast-math rewrite: single __expf shared by BCE-log and sigmoid, branchless,
// fp32 per-thread accumulation (16 bounded terms).
// ---------------------------------------------------------------------------
__global__ __launch_bounds__(256) void k_bce_pool(
    const float* __restrict__ logits,
    const int*   __restrict__ labels,
    float*  __restrict__ pla,
    float*  __restrict__ ppr,
    double* __restrict__ accum)   // [0]=bce_sum [1]=valid_pixels [2]=rmi
{
    int idx = blockIdx.x*blockDim.x + threadIdx.x;
    float bce = 0.f;
    int   vc  = 0;
    if (idx < NC*PP) {
        int nc  = idx / PP;
        int n   = nc / NCLS;
        int c   = nc % NCLS;
        int rem = idx - nc*PP;
        int ph  = rem / PWD;
        int pw  = rem - ph*PWD;
        int r0 = 4*ph - 2, c0 = 4*pw - 2;
        int rlo = max(r0, 0), rhi = min(r0 + 4, HH);
        int clo = max(c0, 0), chi = min(c0 + 4, WW);
        const float* lg = logits + ((size_t)n*NCLS + c)*((size_t)HH*WW);
        const int*   lb = labels + (size_t)n*((size_t)HH*WW);
        float psum  = 0.f;
        int   lasum = 0;
        for (int r = rlo; r < rhi; ++r) {
            for (int cl = clo; cl < chi; ++cl) {
                int   lab   = lb[r*WW + cl];
                float x     = lg[r*WW + cl];
                bool  valid = (lab < NCLS);
                float t     = (lab == c) ? 1.f : 0.f;
                lasum      += (lab == c) ? 1 : 0;
                float ax = fabsf(x);
                float u  = __expf(-ax);              // e^{-|x|}, shared
                float lp = __logf(1.f + u);          // log1p(e^{-|x|})
                float el = fmaxf(x, 0.f) - x*t + lp; // BCE element
                bce += valid ? el : 0.f;
                float r1 = __builtin_amdgcn_rcpf(1.f + u);
                float sg = (x >= 0.f) ? r1 : u*r1;   // sigmoid(x)
                psum += 1e-6f + (valid ? sg : 0.f);  // CLP_MIN for every in-image pixel
                vc   += valid ? 1 : 0;
            }
        }
        pla[idx] = (float)lasum * 0.0625f;
        ppr[idx] = psum * 0.0625f;                   // count_include_pad: /16 always
        if (c != 0) vc = 0;                          // count each pixel once
    }
    double bced = (double)bce;
    double vcd  = (double)vc;
    for (int off = 32; off > 0; off >>= 1) {
        bced += __shfl_down(bced, off);
        vcd  += __shfl_down(vcd,  off);
    }
    __shared__ double sb[4], sv[4];
    int wid = threadIdx.x >> 6, lane = threadIdx.x & 63;
    if (lane == 0) { sb[wid] = bced; sv[wid] = vcd; }
    __syncthreads();
    if (threadIdx.x == 0) {
        atomicAdd(&accum[0], sb[0]+sb[1]+sb[2]+sb[3]);
        atomicAdd(&accum[1], sv[0]+sv[1]+sv[2]+sv[3]);
    }
}

// ---------------------------------------------------------------------------
// Kernel 2: Gram matrix G = W W^T, W = [la views 0..8; pr views 0..8; ones]
// (19 x 16129 per (n,c)). One wave handles G-rows (D0, D0+1); lanes stride j.
// v2: float staging (halved staging VGPRs), 9 waves/block (LDS staged once),
// 8-row strips for 2x block count.
// ---------------------------------------------------------------------------
template<int D0>
__device__ __forceinline__ void row_pair(const float* __restrict__ sla,
                                         const float* __restrict__ spr,
                                         int ni, double* __restrict__ g)
{
    constexpr int NV  = 18 - D0;   // values W_{D0}..W_{17}
    constexpr int NA  = 19 - D0;   // row D0 accs: pairs e=D0..17 + ones-sum
    constexpr int NB  = 18 - D0;   // row D0+1 accs
    double accA[NA];
    double accB[NB];
    #pragma unroll
    for (int k = 0; k < NA; k++) accA[k] = 0.0;
    #pragma unroll
    for (int k = 0; k < NB; k++) accB[k] = 0.0;
    const int lane = threadIdx.x & 63;
    for (int i = 0; i < ni; i++) {
        for (int j = lane; j < 127; j += 64) {
            float v[NV];
            #pragma unroll
            for (int k = 0; k < NV; k++) {
                const float* buf = (D0 + k < 9) ? sla : spr;
                int er = (D0 + k < 9) ? (D0 + k) : (D0 + k - 9);
                v[k] = buf[(i + er/3)*129 + j + (er%3)];
            }
            double vD  = (double)v[0];
            double vD1 = (double)v[1];
            #pragma unroll
            for (int k = 0; k < NV; k++) {
                double dv = (double)v[k];
                accA[k] += vD * dv;
                if (k >= 1) accB[k-1] += vD1 * dv;
            }
            accA[NV] += vD;    // ones-row sum for row D0
            accB[NV-1] += vD1; // ones-row sum for row D0+1
        }
    }
    #pragma unroll
    for (int k = 0; k < NA; k++) {
        double a = accA[k];
        for (int off = 32; off > 0; off >>= 1) a += __shfl_down(a, off);
        if (lane == 0) atomicAdd(&g[D0*19 + D0 + k], a);
    }
    #pragma unroll
    for (int k = 0; k < NB; k++) {
        double a = accB[k];
        for (int off = 32; off > 0; off >>= 1) a += __shfl_down(a, off);
        if (lane == 0) atomicAdd(&g[(D0+1)*19 + (D0+1) + k], a);
    }
}

__global__ __launch_bounds__(576) void k_gram(
    const float* __restrict__ pla,
    const float* __restrict__ ppr,
    double* __restrict__ grams)
{
    __shared__ float sla[10*129];
    __shared__ float spr[10*129];
    int bid = blockIdx.x;
    int nc  = bid / NSTRIP;
    int s   = bid % NSTRIP;
    int i0  = s*8;
    int ni  = min(8, 127 - i0);     // last strip: 7
    int rows = ni + 2;
    const float* gla = pla + (size_t)nc*PP + (size_t)i0*PWD;
    const float* gpr = ppr + (size_t)nc*PP + (size_t)i0*PWD;
    for (int t = threadIdx.x; t < rows*129; t += 576) {
        sla[t] = gla[t];
        spr[t] = gpr[t];
    }
    __syncthreads();
    int w  = threadIdx.x >> 6;        // wave 0..8
    int D0 = 2*w;                     // 0,2,...,16
    double* g = grams + (size_t)nc*GS;
    switch (D0) {
        case 0:  row_pair<0 >(sla, spr, ni, g); break;
        case 2:  row_pair<2 >(sla, spr, ni, g); break;
        case 4:  row_pair<4 >(sla, spr, ni, g); break;
        case 6:  row_pair<6 >(sla, spr, ni, g); break;
        case 8:  row_pair<8 >(sla, spr, ni, g); break;
        case 10: row_pair<10>(sla, spr, ni, g); break;
        case 12: row_pair<12>(sla, spr, ni, g); break;
        case 14: row_pair<14>(sla, spr, ni, g); break;
        case 16: row_pair<16>(sla, spr, ni, g); break;
    }
}

// ---------------------------------------------------------------------------
// Kernel 3: per-(n,c) 9x9 fp64 linear algebra.
// appro_var = la_cov - M P^-1 M^T with P = pr_cov + aI: chol(P)=LL^T,
// Y = L^-1 M^T  ->  M P^-1 M^T = Y^T Y. Then chol(appro_var + aI), logdet.
// ---------------------------------------------------------------------------
__global__ __launch_bounds__(128) void k_solve(
    const double* __restrict__ grams,
    double* __restrict__ accum)
{
    int nc = blockIdx.x;
    const double* g = grams + (size_t)nc*GS;
    __shared__ double P[81], M[81], A[81], Y[81], mla[9], mpr[9];
    int t = threadIdx.x;
    if (t < 9) {
        mla[t] = g[t*19 + 18]     / KPOS;
        mpr[t] = g[(9+t)*19 + 18] / KPOS;
    }
    __syncthreads();
    if (t < 81) {
        int d = t/9, e = t - 9*(t/9);
        double Gll = (d <= e) ? g[d*19 + e]         : g[e*19 + d];
        double Gpp = (d <= e) ? g[(9+d)*19 + 9+e]   : g[(9+e)*19 + 9+d];
        double Glp = g[d*19 + 9 + e];   // la row d (<9) vs pr row 9+e: always upper
        A[t] = Gll - KPOS*mla[d]*mla[e];                                // la_cov
        P[t] = Gpp - KPOS*mpr[d]*mpr[e] + ((d == e) ? POS_ALPHA : 0.0); // pr_cov + aI
        M[t] = Glp - KPOS*mla[d]*mpr[e];                                // la_pr
    }
    __syncthreads();
    // Cholesky of P (lower, in place)
    for (int k = 0; k < 9; k++) {
        if (t == 0) P[k*9+k] = sqrt(P[k*9+k]);
        __syncthreads();
        if (t > k && t < 9) P[t*9+k] /= P[k*9+k];
        __syncthreads();
        if (t < 81) {
            int i = t/9, j = t - 9*(t/9);
            if (i > k && j > k && j <= i) P[i*9+j] -= P[i*9+k]*P[j*9+k];
        }
        __syncthreads();
    }
    // forward solve: column t of Y = L^-1 M^T  (M^T[i][t] = M[t][i])
    if (t < 9) {
        double y[9];
        #pragma unroll
        for (int i = 0; i < 9; i++) {
            double sY = M[t*9 + i];
            #pragma unroll
            for (int m2 = 0; m2 < i; m2++) sY -= P[i*9+m2]*y[m2];
            y[i] = sY / P[i*9+i];
        }
        #pragma unroll
        for (int i = 0; i < 9; i++) Y[i*9 + t] = y[i];
    }
    __syncthreads();
    if (t < 81) {
        int d = t/9, e = t - 9*(t/9);
        double sY = 0.0;
        #pragma unroll
        for (int k = 0; k < 9; k++) sY += Y[k*9+d]*Y[k*9+e];
        A[t] = A[t] - sY + ((d == e) ? POS_ALPHA : 0.0);
    }
    __syncthreads();
    // Cholesky of appro_var + aI
    for (int k = 0; k < 9; k++) {
        if (t == 0) A[k*9+k] = sqrt(A[k*9+k]);
        __syncthreads();
        if (t > k && t < 9) A[t*9+k] /= A[k*9+k];
        __syncthreads();
        if (t < 81) {
            int i = t/9, j = t - 9*(t/9);
            if (i > k && j > k && j <= i) A[i*9+j] -= A[i*9+k]*A[j*9+k];
        }
        __syncthreads();
    }
    if (t == 0) {
        double ld = 0.0;
        for (int k = 0; k < 9; k++) ld += log(A[k*9+k]);
        // rmi contribution: 0.5*logdet / (N * HALF_D) = ld / 36
        atomicAdd(&accum[2], ld * (1.0/36.0));
    }
}

__global__ void k_final(const double* __restrict__ accum, float* __restrict__ out)
{
    if (threadIdx.x == 0 && blockIdx.x == 0) {
        double bce = accum[0] / (accum[1] + 1.0);
        out[0] = (float)(0.5*bce + 0.5*accum[2]);   // LAMBDA = 0.5
    }
}

// ---------------------------------------------------------------------------
extern "C" void kernel_launch(void* const* d_in, const int* in_sizes, int n_in,
                              void* d_out, int out_size, void* d_ws, size_t ws_size,
                              hipStream_t stream)
{
    const float* logits = (const float*)d_in[0];
    const int*   labels = (const int*)d_in[1];
    float* out = (float*)d_out;

    float*  pla   = (float*)d_ws;                       // NC*PP floats (5.06 MB)
    float*  ppr   = pla + (size_t)NC*PP;                // NC*PP floats
    double* grams = (double*)(ppr + (size_t)NC*PP);     // NC*361 doubles
    double* accum = grams + (size_t)NC*GS;              // 4 doubles

    // ws is re-poisoned 0xAA before every launch: zero gram+accum region
    hipMemsetAsync(grams, 0, ((size_t)NC*GS + 4)*sizeof(double), stream);

    int total = NC*PP;
    k_bce_pool<<<(total + 255)/256, 256, 0, stream>>>(logits, labels, pla, ppr, accum);
    k_gram<<<NC*NSTRIP, 576, 0, stream>>>(pla, ppr, grams);
    k_solve<<<NC, 128, 0, stream>>>(grams, accum);
    k_final<<<1, 64, 0, stream>>>(accum, out);
}

// Round 3
// 288.511 us; speedup vs baseline: 1.0302x; 1.0302x over previous
//
#include <hip/hip_runtime.h>
#include <math.h>

#define NCLS 19
#define NBATCH 4
#define HH 512
#define WW 512
#define PHD 129
#define PWD 129
#define PP (PHD*PWD)          // 16641
#define NC (NBATCH*NCLS)      // 76
#define KPOS 16129.0          // 127*127
#define NSTRIP 4              // i-strips of 32 rows for k_gram
#define GS 361                // gram stride per (n,c)
#define POS_ALPHA 5e-4

// ---------------------------------------------------------------------------
// Kernel 1 v3: streaming BCE + pool. Block = (nc, 2 pooled rows).
// Thread t: pooled row p = 2*pg + (t>>7), col-group j = t&127 (cols 4j..4j+3).
// Coalesced float4/int4 loads over the 4 input rows of window p.
// Window j gets (cols 4j-2,4j-1) = right pair of thread j-1 (via LDS halo)
// plus (cols 4j,4j+1) = left pair of thread j. Window 128 = right pair of 127.
// ---------------------------------------------------------------------------
__global__ void k_bce_pool(
    const float* __restrict__ logits,
    const int*   __restrict__ labels,
    float*  __restrict__ pla,
    float*  __restrict__ ppr,
    double* __restrict__ accum)   // [0]=bce_sum [1]=valid_pixels [2]=rmi
{
    int nc = blockIdx.x / 65;
    int pg = blockIdx.x % 65;
    int n  = nc / NCLS;
    int c  = nc % NCLS;
    int half = threadIdx.x >> 7;
    int j    = threadIdx.x & 127;
    int p    = 2*pg + half;          // 0..129 (129 invalid)

    float bce = 0.f; int vc = 0;
    float Lpr = 0.f, Rpr = 0.f;
    int   Lla = 0,   Rla = 0;

    if (p <= 128) {
        const float* lg = logits + (size_t)nc * (size_t)(HH*WW);
        const int*   lb = labels + (size_t)n  * (size_t)(HH*WW);
        int r0 = 4*p - 2;
        float4 xr[4]; int4 lr[4]; bool rv[4];
        #pragma unroll
        for (int dr = 0; dr < 4; dr++) {
            int r = r0 + dr;
            rv[dr] = (r >= 0) && (r < HH);
            int rr = rv[dr] ? r : 0;
            xr[dr] = *(const float4*)(lg + (size_t)rr*WW + 4*j);
            lr[dr] = *(const int4*)  (lb + (size_t)rr*WW + 4*j);
        }
        #pragma unroll
        for (int dr = 0; dr < 4; dr++) {
            float pbase = rv[dr] ? 1e-6f : 0.f;   // CLP_MIN for in-image pixels only
            float xs[4] = {xr[dr].x, xr[dr].y, xr[dr].z, xr[dr].w};
            int   ls[4] = {lr[dr].x, lr[dr].y, lr[dr].z, lr[dr].w};
            #pragma unroll
            for (int e = 0; e < 4; e++) {
                float x   = xs[e];
                int   lab = ls[e];
                bool valid = rv[dr] && (lab < NCLS);
                bool hit   = valid && (lab == c);
                float ax = fabsf(x);
                float u  = __expf(-ax);               // e^{-|x|}
                float lp = __logf(1.f + u);           // log1p(e^{-|x|})
                float el = fmaxf(x, 0.f) - (hit ? x : 0.f) + lp;
                bce += valid ? el : 0.f;
                float r1 = __builtin_amdgcn_rcpf(1.f + u);
                float sg = (x >= 0.f) ? r1 : u*r1;    // sigmoid(x)
                float pe = pbase + (valid ? sg : 0.f);
                if (e < 2) { Lpr += pe; Lla += hit ? 1 : 0; }
                else       { Rpr += pe; Rla += hit ? 1 : 0; }
                vc += valid ? 1 : 0;
            }
        }
    }

    __shared__ float s_rpr[2][128];
    __shared__ float s_rla[2][128];
    s_rpr[half][j] = Rpr;
    s_rla[half][j] = (float)Rla;
    __syncthreads();
    if (p <= 128) {
        float wpr = Lpr        + (j > 0 ? s_rpr[half][j-1] : 0.f);
        float wla = (float)Lla + (j > 0 ? s_rla[half][j-1] : 0.f);
        size_t o = (size_t)nc*PP + (size_t)p*PWD;
        ppr[o + j] = wpr * 0.0625f;
        pla[o + j] = wla * 0.0625f;
        if (j == 127) {                 // window 128: cols 510,511 only
            ppr[o + 128] = Rpr * 0.0625f;
            pla[o + 128] = (float)Rla * 0.0625f;
        }
    }
    if (c != 0) vc = 0;                 // count each pixel once globally
    double bced = (double)bce, vcd = (double)vc;
    for (int off = 32; off > 0; off >>= 1) {
        bced += __shfl_down(bced, off);
        vcd  += __shfl_down(vcd,  off);
    }
    __shared__ double sb[4], sv[4];
    int wid = threadIdx.x >> 6, lane = threadIdx.x & 63;
    if (lane == 0) { sb[wid] = bced; sv[wid] = vcd; }
    __syncthreads();
    if (threadIdx.x == 0) {
        atomicAdd(&accum[0], sb[0]+sb[1]+sb[2]+sb[3]);
        atomicAdd(&accum[1], sv[0]+sv[1]+sv[2]+sv[3]);
    }
}

// ---------------------------------------------------------------------------
// Kernel 2 v3: Gram G = W W^T, W = [la views 0..8; pr views 0..8; ones],
// per (n,c). 5 waves/block with BALANCED row sets (42 fp64 accs each):
// {0,1,16,17} {2,3,14,15} {4,5,12,13} {6,7,10,11} {8,9}.
// Lanes cover j = lane and lane+64 (j<127). NSTRIP=4 -> reduction paid rarely.
// ---------------------------------------------------------------------------
template<int R0,int R1,int R2,int R3,int NR>
__device__ __forceinline__ void gram_rows(const float* __restrict__ sla,
                                          const float* __restrict__ spr,
                                          int ni, double* __restrict__ g)
{
    constexpr int KMIN = R0;
    constexpr int NVW  = 18 - KMIN;
    constexpr int O0 = 0;
    constexpr int O1 = O0 + (19 - R0);
    constexpr int O2 = (NR > 1) ? O1 + (19 - R1) : O1;
    constexpr int O3 = (NR > 2) ? O2 + (19 - R2) : O2;
    constexpr int NACC = (NR>0?19-R0:0)+(NR>1?19-R1:0)+(NR>2?19-R2:0)+(NR>3?19-R3:0);
    double acc[NACC];
    #pragma unroll
    for (int k = 0; k < NACC; k++) acc[k] = 0.0;
    const int lane = threadIdx.x & 63;

    for (int i = 0; i < ni; i++) {
        #pragma unroll
        for (int jj = 0; jj < 2; jj++) {
            int j = lane + 64*jj;
            bool ok = (j < 127);
            double dv[NVW];
            #pragma unroll
            for (int e = KMIN; e < 18; e++) {
                const float* buf = (e < 9) ? sla : spr;
                const int f = (e < 9) ? e : e - 9;
                float x = buf[(i + f/3)*129 + j + (f%3)];
                dv[e-KMIN] = (double)(ok ? x : 0.f);
            }
            {   double vr = dv[R0-KMIN];
                #pragma unroll
                for (int e = R0; e < 18; e++) acc[O0+e-R0] += vr*dv[e-KMIN];
                acc[O0+18-R0] += vr; }
            if constexpr (NR > 1) {
                double vr = dv[R1-KMIN];
                #pragma unroll
                for (int e = R1; e < 18; e++) acc[O1+e-R1] += vr*dv[e-KMIN];
                acc[O1+18-R1] += vr; }
            if constexpr (NR > 2) {
                double vr = dv[R2-KMIN];
                #pragma unroll
                for (int e = R2; e < 18; e++) acc[O2+e-R2] += vr*dv[e-KMIN];
                acc[O2+18-R2] += vr; }
            if constexpr (NR > 3) {
                double vr = dv[R3-KMIN];
                #pragma unroll
                for (int e = R3; e < 18; e++) acc[O3+e-R3] += vr*dv[e-KMIN];
                acc[O3+18-R3] += vr; }
        }
    }
    #pragma unroll
    for (int s = 0; s < NR; s++) {
        const int R = (s==0)?R0:(s==1)?R1:(s==2)?R2:R3;
        const int O = (s==0)?O0:(s==1)?O1:(s==2)?O2:O3;
        #pragma unroll
        for (int e = R; e <= 18; e++) {          // e==18 is the ones-row sum
            double a = acc[O + e - R];
            for (int off = 32; off > 0; off >>= 1) a += __shfl_down(a, off);
            if (lane == 0) atomicAdd(&g[R*19 + e], a);
        }
    }
}

__global__ __launch_bounds__(320) void k_gram(
    const float* __restrict__ pla,
    const float* __restrict__ ppr,
    double* __restrict__ grams)
{
    __shared__ float sla[34*129 + 4];
    __shared__ float spr[34*129 + 4];
    int nc = blockIdx.x / NSTRIP;
    int s  = blockIdx.x % NSTRIP;
    int i0 = s*32;
    int ni = min(32, 127 - i0);       // 32,32,32,31
    int rows = ni + 2;
    const float* gla = pla + (size_t)nc*PP + (size_t)i0*PWD;
    const float* gpr = ppr + (size_t)nc*PP + (size_t)i0*PWD;
    for (int t = threadIdx.x; t < rows*129; t += 320) {
        sla[t] = gla[t];
        spr[t] = gpr[t];
    }
    __syncthreads();
    int w = threadIdx.x >> 6;
    double* g = grams + (size_t)nc*GS;
    switch (w) {
        case 0: gram_rows<0,1,16,17,4>(sla, spr, ni, g); break;
        case 1: gram_rows<2,3,14,15,4>(sla, spr, ni, g); break;
        case 2: gram_rows<4,5,12,13,4>(sla, spr, ni, g); break;
        case 3: gram_rows<6,7,10,11,4>(sla, spr, ni, g); break;
        case 4: gram_rows<8,9,17,17,2>(sla, spr, ni, g); break;
    }
}

// ---------------------------------------------------------------------------
// Kernel 3: per-(n,c) 9x9 fp64 linear algebra.
// appro_var = la_cov - M P^-1 M^T with P = pr_cov + aI: chol(P)=LL^T,
// Y = L^-1 M^T  ->  M P^-1 M^T = Y^T Y. Then chol(appro_var + aI), logdet.
// ---------------------------------------------------------------------------
__global__ __launch_bounds__(128) void k_solve(
    const double* __restrict__ grams,
    double* __restrict__ accum)
{
    int nc = blockIdx.x;
    const double* g = grams + (size_t)nc*GS;
    __shared__ double P[81], M[81], A[81], Y[81], mla[9], mpr[9];
    int t = threadIdx.x;
    if (t < 9) {
        mla[t] = g[t*19 + 18]     / KPOS;
        mpr[t] = g[(9+t)*19 + 18] / KPOS;
    }
    __syncthreads();
    if (t < 81) {
        int d = t/9, e = t - 9*(t/9);
        double Gll = (d <= e) ? g[d*19 + e]         : g[e*19 + d];
        double Gpp = (d <= e) ? g[(9+d)*19 + 9+e]   : g[(9+e)*19 + 9+d];
        double Glp = g[d*19 + 9 + e];   // la row d (<9) vs pr col 9+e: always upper
        A[t] = Gll - KPOS*mla[d]*mla[e];                                // la_cov
        P[t] = Gpp - KPOS*mpr[d]*mpr[e] + ((d == e) ? POS_ALPHA : 0.0); // pr_cov + aI
        M[t] = Glp - KPOS*mla[d]*mpr[e];                                // la_pr
    }
    __syncthreads();
    for (int k = 0; k < 9; k++) {
        if (t == 0) P[k*9+k] = sqrt(P[k*9+k]);
        __syncthreads();
        if (t > k && t < 9) P[t*9+k] /= P[k*9+k];
        __syncthreads();
        if (t < 81) {
            int i = t/9, jx = t - 9*(t/9);
            if (i > k && jx > k && jx <= i) P[i*9+jx] -= P[i*9+k]*P[jx*9+k];
        }
        __syncthreads();
    }
    if (t < 9) {
        double y[9];
        #pragma unroll
        for (int i = 0; i < 9; i++) {
            double sY = M[t*9 + i];
            #pragma unroll
            for (int m2 = 0; m2 < i; m2++) sY -= P[i*9+m2]*y[m2];
            y[i] = sY / P[i*9+i];
        }
        #pragma unroll
        for (int i = 0; i < 9; i++) Y[i*9 + t] = y[i];
    }
    __syncthreads();
    if (t < 81) {
        int d = t/9, e = t - 9*(t/9);
        double sY = 0.0;
        #pragma unroll
        for (int k = 0; k < 9; k++) sY += Y[k*9+d]*Y[k*9+e];
        A[t] = A[t] - sY + ((d == e) ? POS_ALPHA : 0.0);
    }
    __syncthreads();
    for (int k = 0; k < 9; k++) {
        if (t == 0) A[k*9+k] = sqrt(A[k*9+k]);
        __syncthreads();
        if (t > k && t < 9) A[t*9+k] /= A[k*9+k];
        __syncthreads();
        if (t < 81) {
            int i = t/9, jx = t - 9*(t/9);
            if (i > k && jx > k && jx <= i) A[i*9+jx] -= A[i*9+k]*A[jx*9+k];
        }
        __syncthreads();
    }
    if (t == 0) {
        double ld = 0.0;
        for (int k = 0; k < 9; k++) ld += log(A[k*9+k]);
        atomicAdd(&accum[2], ld * (1.0/36.0));  // 0.5*logdet / (N*HALF_D)
    }
}

__global__ void k_final(const double* __restrict__ accum, float* __restrict__ out)
{
    if (threadIdx.x == 0 && blockIdx.x == 0) {
        double bce = accum[0] / (accum[1] + 1.0);
        out[0] = (float)(0.5*bce + 0.5*accum[2]);   // LAMBDA = 0.5
    }
}

// ---------------------------------------------------------------------------
extern "C" void kernel_launch(void* const* d_in, const int* in_sizes, int n_in,
                              void* d_out, int out_size, void* d_ws, size_t ws_size,
                              hipStream_t stream)
{
    const float* logits = (const float*)d_in[0];
    const int*   labels = (const int*)d_in[1];
    float* out = (float*)d_out;

    float*  pla   = (float*)d_ws;                       // NC*PP floats
    float*  ppr   = pla + (size_t)NC*PP;                // NC*PP floats
    double* grams = (double*)(ppr + (size_t)NC*PP);     // NC*361 doubles
    double* accum = grams + (size_t)NC*GS;              // 4 doubles

    hipMemsetAsync(grams, 0, ((size_t)NC*GS + 4)*sizeof(double), stream);

    k_bce_pool<<<NC*65, 256, 0, stream>>>(logits, labels, pla, ppr, accum);
    k_gram<<<NC*NSTRIP, 320, 0, stream>>>(pla, ppr, grams);
    k_solve<<<NC, 128, 0, stream>>>(grams, accum);
    k_final<<<1, 64, 0, stream>>>(accum, out);
}

// Round 5
// 194.544 us; speedup vs baseline: 1.5278x; 1.4830x over previous
//
#include <hip/hip_runtime.h>
#include <math.h>

#define NCLS 19
#define NBATCH 4
#define HH 512
#define WW 512
#define PHD 129
#define PWD 129
#define PP (PHD*PWD)          // 16641
#define NC (NBATCH*NCLS)      // 76
#define KPOS 16129.0          // 127*127
#define NSTRIP 16             // 8-row strips for k_gram
#define NBLK_BCE (NC*65)      // 4940
#define POS_ALPHA 5e-4
// compact upper-triangle offset: row R starts at R*(39-R)/2, 190 entries total
#define OFFU(R) ((R)*(39-(R))/2)

// ---------------------------------------------------------------------------
// Kernel 1 v4: streaming BCE + pool (identical math to v3) — NO ATOMICS.
// Block partials -> part_bce[blockIdx].
// ---------------------------------------------------------------------------
__global__ void k_bce_pool(
    const float* __restrict__ logits,
    const int*   __restrict__ labels,
    float*  __restrict__ pla,
    float*  __restrict__ ppr,
    double2* __restrict__ part_bce)
{
    int nc = blockIdx.x / 65;
    int pg = blockIdx.x % 65;
    int n  = nc / NCLS;
    int c  = nc % NCLS;
    int half = threadIdx.x >> 7;
    int j    = threadIdx.x & 127;
    int p    = 2*pg + half;          // 0..129 (129 invalid)

    float bce = 0.f; int vc = 0;
    float Lpr = 0.f, Rpr = 0.f;
    int   Lla = 0,   Rla = 0;

    if (p <= 128) {
        const float* lg = logits + (size_t)nc * (size_t)(HH*WW);
        const int*   lb = labels + (size_t)n  * (size_t)(HH*WW);
        int r0 = 4*p - 2;
        float4 xr[4]; int4 lr[4]; bool rv[4];
        #pragma unroll
        for (int dr = 0; dr < 4; dr++) {
            int r = r0 + dr;
            rv[dr] = (r >= 0) && (r < HH);
            int rr = rv[dr] ? r : 0;
            xr[dr] = *(const float4*)(lg + (size_t)rr*WW + 4*j);
            lr[dr] = *(const int4*)  (lb + (size_t)rr*WW + 4*j);
        }
        #pragma unroll
        for (int dr = 0; dr < 4; dr++) {
            float pbase = rv[dr] ? 1e-6f : 0.f;   // CLP_MIN for in-image pixels only
            float xs[4] = {xr[dr].x, xr[dr].y, xr[dr].z, xr[dr].w};
            int   ls[4] = {lr[dr].x, lr[dr].y, lr[dr].z, lr[dr].w};
            #pragma unroll
            for (int e = 0; e < 4; e++) {
                float x   = xs[e];
                int   lab = ls[e];
                bool valid = rv[dr] && (lab < NCLS);
                bool hit   = valid && (lab == c);
                float ax = fabsf(x);
                float u  = __expf(-ax);               // e^{-|x|}
                float lp = __logf(1.f + u);           // log1p(e^{-|x|})
                float el = fmaxf(x, 0.f) - (hit ? x : 0.f) + lp;
                bce += valid ? el : 0.f;
                float r1 = __builtin_amdgcn_rcpf(1.f + u);
                float sg = (x >= 0.f) ? r1 : u*r1;    // sigmoid(x)
                float pe = pbase + (valid ? sg : 0.f);
                if (e < 2) { Lpr += pe; Lla += hit ? 1 : 0; }
                else       { Rpr += pe; Rla += hit ? 1 : 0; }
                vc += valid ? 1 : 0;
            }
        }
    }

    __shared__ float s_rpr[2][128];
    __shared__ float s_rla[2][128];
    s_rpr[half][j] = Rpr;
    s_rla[half][j] = (float)Rla;
    __syncthreads();
    if (p <= 128) {
        float wpr = Lpr        + (j > 0 ? s_rpr[half][j-1] : 0.f);
        float wla = (float)Lla + (j > 0 ? s_rla[half][j-1] : 0.f);
        size_t o = (size_t)nc*PP + (size_t)p*PWD;
        ppr[o + j] = wpr * 0.0625f;
        pla[o + j] = wla * 0.0625f;
        if (j == 127) {                 // window 128: cols 510,511 only
            ppr[o + 128] = Rpr * 0.0625f;
            pla[o + 128] = (float)Rla * 0.0625f;
        }
    }
    if (c != 0) vc = 0;                 // count each pixel once globally
    double bced = (double)bce, vcd = (double)vc;
    for (int off = 32; off > 0; off >>= 1) {
        bced += __shfl_down(bced, off);
        vcd  += __shfl_down(vcd,  off);
    }
    __shared__ double sb[4], sv[4];
    int wid = threadIdx.x >> 6, lane = threadIdx.x & 63;
    if (lane == 0) { sb[wid] = bced; sv[wid] = vcd; }
    __syncthreads();
    if (threadIdx.x == 0)
        part_bce[blockIdx.x] = make_double2(sb[0]+sb[1]+sb[2]+sb[3],
                                            sv[0]+sv[1]+sv[2]+sv[3]);
}

// ---------------------------------------------------------------------------
// Kernel 2 v4: Gram G = W W^T, W = [la views 0..8; pr views 0..8; ones].
// 5 waves/block, balanced row sets; per-(nc,strip) compact partials, NO ATOMICS.
// ---------------------------------------------------------------------------
template<int R0,int R1,int R2,int R3,int NR>
__device__ __forceinline__ void gram_rows(const float* __restrict__ sla,
                                          const float* __restrict__ spr,
                                          int ni, double* __restrict__ pg)
{
    constexpr int KMIN = R0;
    constexpr int NVW  = 18 - KMIN;
    constexpr int O0 = 0;
    constexpr int O1 = O0 + (19 - R0);
    constexpr int O2 = (NR > 1) ? O1 + (19 - R1) : O1;
    constexpr int O3 = (NR > 2) ? O2 + (19 - R2) : O2;
    constexpr int NACC = (NR>0?19-R0:0)+(NR>1?19-R1:0)+(NR>2?19-R2:0)+(NR>3?19-R3:0);
    double acc[NACC];
    #pragma unroll
    for (int k = 0; k < NACC; k++) acc[k] = 0.0;
    const int lane = threadIdx.x & 63;

    for (int i = 0; i < ni; i++) {
        #pragma unroll
        for (int jj = 0; jj < 2; jj++) {
            int j = lane + 64*jj;
            bool ok = (j < 127);
            double dv[NVW];
            #pragma unroll
            for (int e = KMIN; e < 18; e++) {
                const float* buf = (e < 9) ? sla : spr;
                const int f = (e < 9) ? e : e - 9;
                float x = buf[(i + f/3)*129 + j + (f%3)];
                dv[e-KMIN] = (double)(ok ? x : 0.f);
            }
            {   double vr = dv[R0-KMIN];
                #pragma unroll
                for (int e = R0; e < 18; e++) acc[O0+e-R0] += vr*dv[e-KMIN];
                acc[O0+18-R0] += vr; }
            if constexpr (NR > 1) {
                double vr = dv[R1-KMIN];
                #pragma unroll
                for (int e = R1; e < 18; e++) acc[O1+e-R1] += vr*dv[e-KMIN];
                acc[O1+18-R1] += vr; }
            if constexpr (NR > 2) {
                double vr = dv[R2-KMIN];
                #pragma unroll
                for (int e = R2; e < 18; e++) acc[O2+e-R2] += vr*dv[e-KMIN];
                acc[O2+18-R2] += vr; }
            if constexpr (NR > 3) {
                double vr = dv[R3-KMIN];
                #pragma unroll
                for (int e = R3; e < 18; e++) acc[O3+e-R3] += vr*dv[e-KMIN];
                acc[O3+18-R3] += vr; }
        }
    }
    #pragma unroll
    for (int s = 0; s < NR; s++) {
        constexpr int RR[4] = {R0, R1, R2, R3};
        const int R = RR[s];
        const int O = (s==0)?O0:(s==1)?O1:(s==2)?O2:O3;
        const int offR = OFFU(R);
        #pragma unroll
        for (int e = R; e <= 18; e++) {          // e==18 is the ones-row sum
            double a = acc[O + e - R];
            for (int off = 32; off > 0; off >>= 1) a += __shfl_down(a, off);
            if (lane == 0) pg[offR + e - R] = a;
        }
    }
}

__global__ __launch_bounds__(320) void k_gram(
    const float* __restrict__ pla,
    const float* __restrict__ ppr,
    double* __restrict__ part_gram)
{
    __shared__ float sla[10*129 + 4];
    __shared__ float spr[10*129 + 4];
    int nc = blockIdx.x / NSTRIP;
    int s  = blockIdx.x % NSTRIP;
    int i0 = s*8;
    int ni = min(8, 127 - i0);       // 8 (last strip: 7)
    int rows = ni + 2;
    const float* gla = pla + (size_t)nc*PP + (size_t)i0*PWD;
    const float* gpr = ppr + (size_t)nc*PP + (size_t)i0*PWD;
    for (int t = threadIdx.x; t < rows*129; t += 320) {
        sla[t] = gla[t];
        spr[t] = gpr[t];
    }
    __syncthreads();
    int w = threadIdx.x >> 6;
    double* pg = part_gram + ((size_t)nc*NSTRIP + s)*190;
    switch (w) {
        case 0: gram_rows<0,1,16,17,4>(sla, spr, ni, pg); break;
        case 1: gram_rows<2,3,14,15,4>(sla, spr, ni, pg); break;
        case 2: gram_rows<4,5,12,13,4>(sla, spr, ni, pg); break;
        case 3: gram_rows<6,7,10,11,4>(sla, spr, ni, pg); break;
        case 4: gram_rows<8,9,17,17,2>(sla, spr, ni, pg); break;
    }
}

// ---------------------------------------------------------------------------
// Kernel 3: sum gram partials, then per-(n,c) 9x9 fp64 algebra.
// appro_var = la_cov - M P^-1 M^T, two Choleskys, logdet -> logdetArr[nc].
// ---------------------------------------------------------------------------
__global__ __launch_bounds__(256) void k_solve(
    const double* __restrict__ part_gram,
    double* __restrict__ logdetArr)
{
    int nc = blockIdx.x;
    __shared__ double gf[361];
    __shared__ double P[81], M[81], A[81], Y[81], mla[9], mpr[9];
    int t = threadIdx.x;
    if (t < 190) {
        int R = 0;
        while (R < 18 && OFFU(R+1) <= t) R++;
        int e = R + (t - OFFU(R));
        double sY = 0.0;
        for (int s = 0; s < NSTRIP; s++)
            sY += part_gram[((size_t)nc*NSTRIP + s)*190 + t];
        gf[R*19 + e] = sY;
    }
    __syncthreads();
    if (t < 9) {
        mla[t] = gf[t*19 + 18]     / KPOS;
        mpr[t] = gf[(9+t)*19 + 18] / KPOS;
    }
    __syncthreads();
    if (t < 81) {
        int d = t/9, e = t - 9*(t/9);
        double Gll = (d <= e) ? gf[d*19 + e]       : gf[e*19 + d];
        double Gpp = (d <= e) ? gf[(9+d)*19 + 9+e] : gf[(9+e)*19 + 9+d];
        double Glp = gf[d*19 + 9 + e];   // la row d (<9) vs pr col 9+e: always upper
        A[t] = Gll - KPOS*mla[d]*mla[e];                                // la_cov
        P[t] = Gpp - KPOS*mpr[d]*mpr[e] + ((d == e) ? POS_ALPHA : 0.0); // pr_cov + aI
        M[t] = Glp - KPOS*mla[d]*mpr[e];                                // la_pr
    }
    __syncthreads();
    for (int k = 0; k < 9; k++) {
        if (t == 0) P[k*9+k] = sqrt(P[k*9+k]);
        __syncthreads();
        if (t > k && t < 9) P[t*9+k] /= P[k*9+k];
        __syncthreads();
        if (t < 81) {
            int i = t/9, jx = t - 9*(t/9);
            if (i > k && jx > k && jx <= i) P[i*9+jx] -= P[i*9+k]*P[jx*9+k];
        }
        __syncthreads();
    }
    if (t < 9) {
        double y[9];
        #pragma unroll
        for (int i = 0; i < 9; i++) {
            double sY = M[t*9 + i];
            #pragma unroll
            for (int m2 = 0; m2 < i; m2++) sY -= P[i*9+m2]*y[m2];
            y[i] = sY / P[i*9+i];
        }
        #pragma unroll
        for (int i = 0; i < 9; i++) Y[i*9 + t] = y[i];
    }
    __syncthreads();
    if (t < 81) {
        int d = t/9, e = t - 9*(t/9);
        double sY = 0.0;
        #pragma unroll
        for (int k = 0; k < 9; k++) sY += Y[k*9+d]*Y[k*9+e];
        A[t] = A[t] - sY + ((d == e) ? POS_ALPHA : 0.0);
    }
    __syncthreads();
    for (int k = 0; k < 9; k++) {
        if (t == 0) A[k*9+k] = sqrt(A[k*9+k]);
        __syncthreads();
        if (t > k && t < 9) A[t*9+k] /= A[k*9+k];
        __syncthreads();
        if (t < 81) {
            int i = t/9, jx = t - 9*(t/9);
            if (i > k && jx > k && jx <= i) A[i*9+jx] -= A[i*9+k]*A[jx*9+k];
        }
        __syncthreads();
    }
    if (t == 0) {
        double ld = 0.0;
        for (int k = 0; k < 9; k++) ld += log(A[k*9+k]);
        logdetArr[nc] = ld;
    }
}

// ---------------------------------------------------------------------------
// Kernel 4: final reduction of 4940 BCE partials + 76 logdets -> loss scalar.
// ---------------------------------------------------------------------------
__global__ __launch_bounds__(256) void k_final(
    const double2* __restrict__ part_bce,
    const double*  __restrict__ logdetArr,
    float* __restrict__ out)
{
    int t = threadIdx.x;
    double b = 0.0, v = 0.0, r = 0.0;
    for (int i = t; i < NBLK_BCE; i += 256) {
        double2 pv = part_bce[i];
        b += pv.x; v += pv.y;
    }
    for (int i = t; i < NC; i += 256) r += logdetArr[i];
    for (int off = 32; off > 0; off >>= 1) {
        b += __shfl_down(b, off);
        v += __shfl_down(v, off);
        r += __shfl_down(r, off);
    }
    __shared__ double sb[4], sv[4], sr[4];
    int wid = t >> 6, lane = t & 63;
    if (lane == 0) { sb[wid] = b; sv[wid] = v; sr[wid] = r; }
    __syncthreads();
    if (t == 0) {
        double bsum = sb[0]+sb[1]+sb[2]+sb[3];
        double vsum = sv[0]+sv[1]+sv[2]+sv[3];
        double rsum = sr[0]+sr[1]+sr[2]+sr[3];
        double bce  = bsum / (vsum + 1.0);
        out[0] = (float)(0.5*bce + 0.5*(rsum * (1.0/36.0)));  // LAMBDA=0.5; /(N*HALF_D)
    }
}

// ---------------------------------------------------------------------------
extern "C" void kernel_launch(void* const* d_in, const int* in_sizes, int n_in,
                              void* d_out, int out_size, void* d_ws, size_t ws_size,
                              hipStream_t stream)
{
    const float* logits = (const float*)d_in[0];
    const int*   labels = (const int*)d_in[1];
    float* out = (float*)d_out;

    float*   pla       = (float*)d_ws;                         // 76*16641 floats
    float*   ppr       = pla + (size_t)NC*PP;
    double*  part_gram = (double*)(ppr + (size_t)NC*PP);       // 76*16*190 doubles
    double2* part_bce  = (double2*)(part_gram + (size_t)NC*NSTRIP*190); // 4940 double2
    double*  logdetArr = (double*)(part_bce + NBLK_BCE);       // 76 doubles
    // total ws use ~12.05 MB; every slot written unconditionally -> no memset

    k_bce_pool<<<NBLK_BCE, 256, 0, stream>>>(logits, labels, pla, ppr, part_bce);
    k_gram<<<NC*NSTRIP, 320, 0, stream>>>(pla, ppr, part_gram);
    k_solve<<<NC, 256, 0, stream>>>(part_gram, logdetArr);
    k_final<<<1, 256, 0, stream>>>(part_bce, logdetArr, out);
}

// Round 7
// 190.045 us; speedup vs baseline: 1.5639x; 1.0237x over previous
//
#include <hip/hip_runtime.h>
#include <math.h>

#define NCLS 19
#define NBATCH 4
#define HH 512
#define WW 512
#define PHD 129
#define PWD 129
#define PP (PHD*PWD)          // 16641
#define NC (NBATCH*NCLS)      // 76
#define KPOS 16129.0          // 127*127
#define NSTRIP 16             // 8-row strips for k_gram
#define NBLK_BCE (NC*65)      // 4940
#define POS_ALPHA 5e-4
// compact upper-triangle offset: row R starts at R*(39-R)/2; entries (R,e) e=R..18
#define OFFU(R) ((R)*(39-(R))/2)

// ---------------------------------------------------------------------------
// Kernel 1: streaming BCE + pool — unchanged from R4 (atomic-free).
// ---------------------------------------------------------------------------
__global__ void k_bce_pool(
    const float* __restrict__ logits,
    const int*   __restrict__ labels,
    float*  __restrict__ pla,
    float*  __restrict__ ppr,
    double2* __restrict__ part_bce)
{
    int nc = blockIdx.x / 65;
    int pg = blockIdx.x % 65;
    int n  = nc / NCLS;
    int c  = nc % NCLS;
    int half = threadIdx.x >> 7;
    int j    = threadIdx.x & 127;
    int p    = 2*pg + half;          // 0..129 (129 invalid)

    float bce = 0.f; int vc = 0;
    float Lpr = 0.f, Rpr = 0.f;
    int   Lla = 0,   Rla = 0;

    if (p <= 128) {
        const float* lg = logits + (size_t)nc * (size_t)(HH*WW);
        const int*   lb = labels + (size_t)n  * (size_t)(HH*WW);
        int r0 = 4*p - 2;
        float4 xr[4]; int4 lr[4]; bool rv[4];
        #pragma unroll
        for (int dr = 0; dr < 4; dr++) {
            int r = r0 + dr;
            rv[dr] = (r >= 0) && (r < HH);
            int rr = rv[dr] ? r : 0;
            xr[dr] = *(const float4*)(lg + (size_t)rr*WW + 4*j);
            lr[dr] = *(const int4*)  (lb + (size_t)rr*WW + 4*j);
        }
        #pragma unroll
        for (int dr = 0; dr < 4; dr++) {
            float pbase = rv[dr] ? 1e-6f : 0.f;   // CLP_MIN for in-image pixels only
            float xs[4] = {xr[dr].x, xr[dr].y, xr[dr].z, xr[dr].w};
            int   ls[4] = {lr[dr].x, lr[dr].y, lr[dr].z, lr[dr].w};
            #pragma unroll
            for (int e = 0; e < 4; e++) {
                float x   = xs[e];
                int   lab = ls[e];
                bool valid = rv[dr] && (lab < NCLS);
                bool hit   = valid && (lab == c);
                float ax = fabsf(x);
                float u  = __expf(-ax);               // e^{-|x|}
                float lp = __logf(1.f + u);           // log1p(e^{-|x|})
                float el = fmaxf(x, 0.f) - (hit ? x : 0.f) + lp;
                bce += valid ? el : 0.f;
                float r1 = __builtin_amdgcn_rcpf(1.f + u);
                float sg = (x >= 0.f) ? r1 : u*r1;    // sigmoid(x)
                float pe = pbase + (valid ? sg : 0.f);
                if (e < 2) { Lpr += pe; Lla += hit ? 1 : 0; }
                else       { Rpr += pe; Rla += hit ? 1 : 0; }
                vc += valid ? 1 : 0;
            }
        }
    }

    __shared__ float s_rpr[2][128];
    __shared__ float s_rla[2][128];
    s_rpr[half][j] = Rpr;
    s_rla[half][j] = (float)Rla;
    __syncthreads();
    if (p <= 128) {
        float wpr = Lpr        + (j > 0 ? s_rpr[half][j-1] : 0.f);
        float wla = (float)Lla + (j > 0 ? s_rla[half][j-1] : 0.f);
        size_t o = (size_t)nc*PP + (size_t)p*PWD;
        ppr[o + j] = wpr * 0.0625f;
        pla[o + j] = wla * 0.0625f;
        if (j == 127) {                 // window 128: cols 510,511 only
            ppr[o + 128] = Rpr * 0.0625f;
            pla[o + 128] = (float)Rla * 0.0625f;
        }
    }
    if (c != 0) vc = 0;                 // count each pixel once globally
    double bced = (double)bce, vcd = (double)vc;
    for (int off = 32; off > 0; off >>= 1) {
        bced += __shfl_down(bced, off);
        vcd  += __shfl_down(vcd,  off);
    }
    __shared__ double sb[4], sv[4];
    int wid = threadIdx.x >> 6, lane = threadIdx.x & 63;
    if (lane == 0) { sb[wid] = bced; sv[wid] = vcd; }
    __syncthreads();
    if (threadIdx.x == 0)
        part_bce[blockIdx.x] = make_double2(sb[0]+sb[1]+sb[2]+sb[3],
                                            sv[0]+sv[1]+sv[2]+sv[3]);
}

// ---------------------------------------------------------------------------
// Kernel 2 v5: Gram G = W W^T, W = [la views 0..8; pr views 0..8; ones].
// 9 waves/block; wave w owns Gram rows {w, 17-w} -> EXACTLY 21 fp64 accs
// (42 VGPRs) + <=18 fp64 staging. No spills (R5 had 42 accs vs VGPR=76 ->
// scratch thrash, 62us latency-bound). (18,18) entry = 127*127 constant,
// dropped from the kernel.
// ---------------------------------------------------------------------------
template<int R>
__device__ __forceinline__ void gram_pair(const float* __restrict__ sla,
                                          const float* __restrict__ spr,
                                          int ni, double* __restrict__ pg)
{
    constexpr int R2 = 17 - R;       // partner row (>= R)
    constexpr int NV = 18 - R;       // staged values v[R..17]
    constexpr int NA = 19 - R;       // row R accs: e=R..18 (18 = ones-sum)
    constexpr int NB = R + 2;        // row R2 accs: e=R2..18
    double acc[NA + NB];
    #pragma unroll
    for (int k = 0; k < NA + NB; k++) acc[k] = 0.0;
    const int lane = threadIdx.x & 63;

    for (int i = 0; i < ni; i++) {
        #pragma unroll
        for (int jj = 0; jj < 2; jj++) {
            int j = lane + 64*jj;
            bool ok = (j < 127);
            double dv[NV];
            #pragma unroll
            for (int e = R; e < 18; e++) {
                const float* buf = (e < 9) ? sla : spr;
                const int f = (e < 9) ? e : e - 9;
                float x = buf[(i + f/3)*129 + j + (f%3)];
                dv[e-R] = (double)(ok ? x : 0.f);
            }
            double vA = dv[0];         // v[R]
            double vB = dv[R2 - R];    // v[R2]
            #pragma unroll
            for (int e = R; e < 18; e++) acc[e-R] += vA * dv[e-R];
            acc[NA-1] += vA;                        // (R,18) row sum
            #pragma unroll
            for (int e = R2; e < 18; e++) acc[NA + e-R2] += vB * dv[e-R];
            acc[NA + NB - 1] += vB;                 // (R2,18) row sum
        }
    }
    #pragma unroll
    for (int k = 0; k < NA; k++) {
        double a = acc[k];
        for (int off = 32; off > 0; off >>= 1) a += __shfl_down(a, off);
        if (lane == 0) pg[OFFU(R) + k] = a;
    }
    #pragma unroll
    for (int k = 0; k < NB; k++) {
        double a = acc[NA + k];
        for (int off = 32; off > 0; off >>= 1) a += __shfl_down(a, off);
        if (lane == 0) pg[OFFU(R2) + k] = a;
    }
}

__global__ __launch_bounds__(576) void k_gram(
    const float* __restrict__ pla,
    const float* __restrict__ ppr,
    double* __restrict__ part_gram)
{
    __shared__ float sla[10*129 + 4];
    __shared__ float spr[10*129 + 4];
    int nc = blockIdx.x / NSTRIP;
    int s  = blockIdx.x % NSTRIP;
    int i0 = s*8;
    int ni = min(8, 127 - i0);       // 8 (last strip: 7)
    int rows = ni + 2;
    const float* gla = pla + (size_t)nc*PP + (size_t)i0*PWD;
    const float* gpr = ppr + (size_t)nc*PP + (size_t)i0*PWD;
    for (int t = threadIdx.x; t < rows*129; t += 576) {
        sla[t] = gla[t];
        spr[t] = gpr[t];
    }
    __syncthreads();
    int w = threadIdx.x >> 6;        // wave 0..8
    double* pg = part_gram + ((size_t)nc*NSTRIP + s)*190;
    switch (w) {
        case 0: gram_pair<0>(sla, spr, ni, pg); break;
        case 1: gram_pair<1>(sla, spr, ni, pg); break;
        case 2: gram_pair<2>(sla, spr, ni, pg); break;
        case 3: gram_pair<3>(sla, spr, ni, pg); break;
        case 4: gram_pair<4>(sla, spr, ni, pg); break;
        case 5: gram_pair<5>(sla, spr, ni, pg); break;
        case 6: gram_pair<6>(sla, spr, ni, pg); break;
        case 7: gram_pair<7>(sla, spr, ni, pg); break;
        case 8: gram_pair<8>(sla, spr, ni, pg); break;
    }
}

// ---------------------------------------------------------------------------
// Kernel 3: sum gram partials (189 entries; (18,18)=KPOS constant), then
// per-(n,c) 9x9 fp64 algebra: appro_var = la_cov - M P^-1 M^T, two
// Choleskys, logdet -> logdetArr[nc].
// ---------------------------------------------------------------------------
__global__ __launch_bounds__(192) void k_solve(
    const double* __restrict__ part_gram,
    double* __restrict__ logdetArr)
{
    int nc = blockIdx.x;
    __shared__ double gf[361];
    __shared__ double P[81], M[81], A[81], Y[81], mla[9], mpr[9];
    int t = threadIdx.x;
    if (t < 189) {
        int R = 0;
        while (R < 17 && OFFU(R+1) <= t) R++;
        int e = R + (t - OFFU(R));
        double sY = 0.0;
        for (int s = 0; s < NSTRIP; s++)
            sY += part_gram[((size_t)nc*NSTRIP + s)*190 + t];
        gf[R*19 + e] = sY;
    }
    __syncthreads();
    if (t < 9) {
        mla[t] = gf[t*19 + 18]     / KPOS;
        mpr[t] = gf[(9+t)*19 + 18] / KPOS;
    }
    __syncthreads();
    if (t < 81) {
        int d = t/9, e = t - 9*(t/9);
        double Gll = (d <= e) ? gf[d*19 + e]       : gf[e*19 + d];
        double Gpp = (d <= e) ? gf[(9+d)*19 + 9+e] : gf[(9+e)*19 + 9+d];
        double Glp = gf[d*19 + 9 + e];   // la row d (<9) vs pr col 9+e: always upper
        A[t] = Gll - KPOS*mla[d]*mla[e];                                // la_cov
        P[t] = Gpp - KPOS*mpr[d]*mpr[e] + ((d == e) ? POS_ALPHA : 0.0); // pr_cov + aI
        M[t] = Glp - KPOS*mla[d]*mpr[e];                                // la_pr
    }
    __syncthreads();
    for (int k = 0; k < 9; k++) {
        if (t == 0) P[k*9+k] = sqrt(P[k*9+k]);
        __syncthreads();
        if (t > k && t < 9) P[t*9+k] /= P[k*9+k];
        __syncthreads();
        if (t < 81) {
            int i = t/9, jx = t - 9*(t/9);
            if (i > k && jx > k && jx <= i) P[i*9+jx] -= P[i*9+k]*P[jx*9+k];
        }
        __syncthreads();
    }
    if (t < 9) {
        double y[9];
        #pragma unroll
        for (int i = 0; i < 9; i++) {
            double sY = M[t*9 + i];
            #pragma unroll
            for (int m2 = 0; m2 < i; m2++) sY -= P[i*9+m2]*y[m2];
            y[i] = sY / P[i*9+i];
        }
        #pragma unroll
        for (int i = 0; i < 9; i++) Y[i*9 + t] = y[i];
    }
    __syncthreads();
    if (t < 81) {
        int d = t/9, e = t - 9*(t/9);
        double sY = 0.0;
        #pragma unroll
        for (int k = 0; k < 9; k++) sY += Y[k*9+d]*Y[k*9+e];
        A[t] = A[t] - sY + ((d == e) ? POS_ALPHA : 0.0);
    }
    __syncthreads();
    for (int k = 0; k < 9; k++) {
        if (t == 0) A[k*9+k] = sqrt(A[k*9+k]);
        __syncthreads();
        if (t > k && t < 9) A[t*9+k] /= A[k*9+k];
        __syncthreads();
        if (t < 81) {
            int i = t/9, jx = t - 9*(t/9);
            if (i > k && jx > k && jx <= i) A[i*9+jx] -= A[i*9+k]*A[jx*9+k];
        }
        __syncthreads();
    }
    if (t == 0) {
        double ld = 0.0;
        for (int k = 0; k < 9; k++) ld += log(A[k*9+k]);
        logdetArr[nc] = ld;
    }
}

// ---------------------------------------------------------------------------
// Kernel 4: final reduction of 4940 BCE partials + 76 logdets -> loss scalar.
// ---------------------------------------------------------------------------
__global__ __launch_bounds__(256) void k_final(
    const double2* __restrict__ part_bce,
    const double*  __restrict__ logdetArr,
    float* __restrict__ out)
{
    int t = threadIdx.x;
    double b = 0.0, v = 0.0, r = 0.0;
    for (int i = t; i < NBLK_BCE; i += 256) {
        double2 pv = part_bce[i];
        b += pv.x; v += pv.y;
    }
    for (int i = t; i < NC; i += 256) r += logdetArr[i];
    for (int off = 32; off > 0; off >>= 1) {
        b += __shfl_down(b, off);
        v += __shfl_down(v, off);
        r += __shfl_down(r, off);
    }
    __shared__ double sb[4], sv[4], sr[4];
    int wid = t >> 6, lane = t & 63;
    if (lane == 0) { sb[wid] = b; sv[wid] = v; sr[wid] = r; }
    __syncthreads();
    if (t == 0) {
        double bsum = sb[0]+sb[1]+sb[2]+sb[3];
        double vsum = sv[0]+sv[1]+sv[2]+sv[3];
        double rsum = sr[0]+sr[1]+sr[2]+sr[3];
        double bce  = bsum / (vsum + 1.0);
        out[0] = (float)(0.5*bce + 0.5*(rsum * (1.0/36.0)));  // LAMBDA=0.5; /(N*HALF_D)
    }
}

// ---------------------------------------------------------------------------
extern "C" void kernel_launch(void* const* d_in, const int* in_sizes, int n_in,
                              void* d_out, int out_size, void* d_ws, size_t ws_size,
                              hipStream_t stream)
{
    const float* logits = (const float*)d_in[0];
    const int*   labels = (const int*)d_in[1];
    float* out = (float*)d_out;

    float*   pla       = (float*)d_ws;                         // 76*16641 floats
    float*   ppr       = pla + (size_t)NC*PP;
    double*  part_gram = (double*)(ppr + (size_t)NC*PP);       // 76*16*190 doubles
    double2* part_bce  = (double2*)(part_gram + (size_t)NC*NSTRIP*190); // 4940 double2
    double*  logdetArr = (double*)(part_bce + NBLK_BCE);       // 76 doubles
    // total ws use ~12.05 MB; every slot read downstream is written -> no memset

    k_bce_pool<<<NBLK_BCE, 256, 0, stream>>>(logits, labels, pla, ppr, part_bce);
    k_gram<<<NC*NSTRIP, 576, 0, stream>>>(pla, ppr, part_gram);
    k_solve<<<NC, 192, 0, stream>>>(part_gram, logdetArr);
    k_final<<<1, 256, 0, stream>>>(part_bce, logdetArr, out);
}

// Round 9
// 189.422 us; speedup vs baseline: 1.5691x; 1.0033x over previous
//
#include <hip/hip_runtime.h>
#include <math.h>

#define NCLS 19
#define NBATCH 4
#define HH 512
#define WW 512
#define PHD 129
#define PWD 129
#define PP (PHD*PWD)          // 16641
#define NC (NBATCH*NCLS)      // 76
#define KPOS 16129.0          // 127*127
#define NSTRIP 16             // 8-row strips for k_gram
#define NBLK_BCE (NC*65)      // 4940
#define POS_ALPHA 5e-4
// compact upper-triangle offset: row R starts at R*(39-R)/2; entries (R,e) e=R..18
#define OFFU(R) ((R)*(39-(R))/2)

// ---------------------------------------------------------------------------
// Kernel 1: streaming BCE + pool — unchanged (atomic-free).
// ---------------------------------------------------------------------------
__global__ void k_bce_pool(
    const float* __restrict__ logits,
    const int*   __restrict__ labels,
    float*  __restrict__ pla,
    float*  __restrict__ ppr,
    double2* __restrict__ part_bce)
{
    int nc = blockIdx.x / 65;
    int pg = blockIdx.x % 65;
    int n  = nc / NCLS;
    int c  = nc % NCLS;
    int half = threadIdx.x >> 7;
    int j    = threadIdx.x & 127;
    int p    = 2*pg + half;          // 0..129 (129 invalid)

    float bce = 0.f; int vc = 0;
    float Lpr = 0.f, Rpr = 0.f;
    int   Lla = 0,   Rla = 0;

    if (p <= 128) {
        const float* lg = logits + (size_t)nc * (size_t)(HH*WW);
        const int*   lb = labels + (size_t)n  * (size_t)(HH*WW);
        int r0 = 4*p - 2;
        float4 xr[4]; int4 lr[4]; bool rv[4];
        #pragma unroll
        for (int dr = 0; dr < 4; dr++) {
            int r = r0 + dr;
            rv[dr] = (r >= 0) && (r < HH);
            int rr = rv[dr] ? r : 0;
            xr[dr] = *(const float4*)(lg + (size_t)rr*WW + 4*j);
            lr[dr] = *(const int4*)  (lb + (size_t)rr*WW + 4*j);
        }
        #pragma unroll
        for (int dr = 0; dr < 4; dr++) {
            float pbase = rv[dr] ? 1e-6f : 0.f;   // CLP_MIN for in-image pixels only
            float xs[4] = {xr[dr].x, xr[dr].y, xr[dr].z, xr[dr].w};
            int   ls[4] = {lr[dr].x, lr[dr].y, lr[dr].z, lr[dr].w};
            #pragma unroll
            for (int e = 0; e < 4; e++) {
                float x   = xs[e];
                int   lab = ls[e];
                bool valid = rv[dr] && (lab < NCLS);
                bool hit   = valid && (lab == c);
                float ax = fabsf(x);
                float u  = __expf(-ax);               // e^{-|x|}
                float lp = __logf(1.f + u);           // log1p(e^{-|x|})
                float el = fmaxf(x, 0.f) - (hit ? x : 0.f) + lp;
                bce += valid ? el : 0.f;
                float r1 = __builtin_amdgcn_rcpf(1.f + u);
                float sg = (x >= 0.f) ? r1 : u*r1;    // sigmoid(x)
                float pe = pbase + (valid ? sg : 0.f);
                if (e < 2) { Lpr += pe; Lla += hit ? 1 : 0; }
                else       { Rpr += pe; Rla += hit ? 1 : 0; }
                vc += valid ? 1 : 0;
            }
        }
    }

    __shared__ float s_rpr[2][128];
    __shared__ float s_rla[2][128];
    s_rpr[half][j] = Rpr;
    s_rla[half][j] = (float)Rla;
    __syncthreads();
    if (p <= 128) {
        float wpr = Lpr        + (j > 0 ? s_rpr[half][j-1] : 0.f);
        float wla = (float)Lla + (j > 0 ? s_rla[half][j-1] : 0.f);
        size_t o = (size_t)nc*PP + (size_t)p*PWD;
        ppr[o + j] = wpr * 0.0625f;
        pla[o + j] = wla * 0.0625f;
        if (j == 127) {                 // window 128: cols 510,511 only
            ppr[o + 128] = Rpr * 0.0625f;
            pla[o + 128] = (float)Rla * 0.0625f;
        }
    }
    if (c != 0) vc = 0;                 // count each pixel once globally
    double bced = (double)bce, vcd = (double)vc;
    for (int off = 32; off > 0; off >>= 1) {
        bced += __shfl_down(bced, off);
        vcd  += __shfl_down(vcd,  off);
    }
    __shared__ double sb[4], sv[4];
    int wid = threadIdx.x >> 6, lane = threadIdx.x & 63;
    if (lane == 0) { sb[wid] = bced; sv[wid] = vcd; }
    __syncthreads();
    if (threadIdx.x == 0)
        part_bce[blockIdx.x] = make_double2(sb[0]+sb[1]+sb[2]+sb[3],
                                            sv[0]+sv[1]+sv[2]+sv[3]);
}

// ---------------------------------------------------------------------------
// Kernel 2 v6: identical to v5 EXCEPT __launch_bounds__(576, 3).
// R7 counters showed VGPR_Count=48 (< the 42 accs + 36 staging needed by
// wave 0) -> compiler's default occupancy heuristic (~10 waves/EU) forced
// spills to scratch. min-3-waves/EU lifts the VGPR cap to ~170 -> no spills.
// ---------------------------------------------------------------------------
template<int R>
__device__ __forceinline__ void gram_pair(const float* __restrict__ sla,
                                          const float* __restrict__ spr,
                                          int ni, double* __restrict__ pg)
{
    constexpr int R2 = 17 - R;       // partner row (>= R)
    constexpr int NV = 18 - R;       // staged values v[R..17]
    constexpr int NA = 19 - R;       // row R accs: e=R..18 (18 = ones-sum)
    constexpr int NB = R + 2;        // row R2 accs: e=R2..18
    double acc[NA + NB];
    #pragma unroll
    for (int k = 0; k < NA + NB; k++) acc[k] = 0.0;
    const int lane = threadIdx.x & 63;

    for (int i = 0; i < ni; i++) {
        #pragma unroll
        for (int jj = 0; jj < 2; jj++) {
            int j = lane + 64*jj;
            bool ok = (j < 127);
            double dv[NV];
            #pragma unroll
            for (int e = R; e < 18; e++) {
                const float* buf = (e < 9) ? sla : spr;
                const int f = (e < 9) ? e : e - 9;
                float x = buf[(i + f/3)*129 + j + (f%3)];
                dv[e-R] = (double)(ok ? x : 0.f);
            }
            double vA = dv[0];         // v[R]
            double vB = dv[R2 - R];    // v[R2]
            #pragma unroll
            for (int e = R; e < 18; e++) acc[e-R] += vA * dv[e-R];
            acc[NA-1] += vA;                        // (R,18) row sum
            #pragma unroll
            for (int e = R2; e < 18; e++) acc[NA + e-R2] += vB * dv[e-R];
            acc[NA + NB - 1] += vB;                 // (R2,18) row sum
        }
    }
    #pragma unroll
    for (int k = 0; k < NA; k++) {
        double a = acc[k];
        for (int off = 32; off > 0; off >>= 1) a += __shfl_down(a, off);
        if (lane == 0) pg[OFFU(R) + k] = a;
    }
    #pragma unroll
    for (int k = 0; k < NB; k++) {
        double a = acc[NA + k];
        for (int off = 32; off > 0; off >>= 1) a += __shfl_down(a, off);
        if (lane == 0) pg[OFFU(R2) + k] = a;
    }
}

__global__ __launch_bounds__(576, 3) void k_gram(
    const float* __restrict__ pla,
    const float* __restrict__ ppr,
    double* __restrict__ part_gram)
{
    __shared__ float sla[10*129 + 4];
    __shared__ float spr[10*129 + 4];
    int nc = blockIdx.x / NSTRIP;
    int s  = blockIdx.x % NSTRIP;
    int i0 = s*8;
    int ni = min(8, 127 - i0);       // 8 (last strip: 7)
    int rows = ni + 2;
    const float* gla = pla + (size_t)nc*PP + (size_t)i0*PWD;
    const float* gpr = ppr + (size_t)nc*PP + (size_t)i0*PWD;
    for (int t = threadIdx.x; t < rows*129; t += 576) {
        sla[t] = gla[t];
        spr[t] = gpr[t];
    }
    __syncthreads();
    int w = threadIdx.x >> 6;        // wave 0..8
    double* pg = part_gram + ((size_t)nc*NSTRIP + s)*190;
    switch (w) {
        case 0: gram_pair<0>(sla, spr, ni, pg); break;
        case 1: gram_pair<1>(sla, spr, ni, pg); break;
        case 2: gram_pair<2>(sla, spr, ni, pg); break;
        case 3: gram_pair<3>(sla, spr, ni, pg); break;
        case 4: gram_pair<4>(sla, spr, ni, pg); break;
        case 5: gram_pair<5>(sla, spr, ni, pg); break;
        case 6: gram_pair<6>(sla, spr, ni, pg); break;
        case 7: gram_pair<7>(sla, spr, ni, pg); break;
        case 8: gram_pair<8>(sla, spr, ni, pg); break;
    }
}

// ---------------------------------------------------------------------------
// Kernel 3: sum gram partials (189 entries; (18,18)=KPOS constant), then
// per-(n,c) 9x9 fp64 algebra: appro_var = la_cov - M P^-1 M^T, two
// Choleskys, logdet -> logdetArr[nc].
// ---------------------------------------------------------------------------
__global__ __launch_bounds__(192) void k_solve(
    const double* __restrict__ part_gram,
    double* __restrict__ logdetArr)
{
    int nc = blockIdx.x;
    __shared__ double gf[361];
    __shared__ double P[81], M[81], A[81], Y[81], mla[9], mpr[9];
    int t = threadIdx.x;
    if (t < 189) {
        int R = 0;
        while (R < 17 && OFFU(R+1) <= t) R++;
        int e = R + (t - OFFU(R));
        double sY = 0.0;
        for (int s = 0; s < NSTRIP; s++)
            sY += part_gram[((size_t)nc*NSTRIP + s)*190 + t];
        gf[R*19 + e] = sY;
    }
    __syncthreads();
    if (t < 9) {
        mla[t] = gf[t*19 + 18]     / KPOS;
        mpr[t] = gf[(9+t)*19 + 18] / KPOS;
    }
    __syncthreads();
    if (t < 81) {
        int d = t/9, e = t - 9*(t/9);
        double Gll = (d <= e) ? gf[d*19 + e]       : gf[e*19 + d];
        double Gpp = (d <= e) ? gf[(9+d)*19 + 9+e] : gf[(9+e)*19 + 9+d];
        double Glp = gf[d*19 + 9 + e];   // la row d (<9) vs pr col 9+e: always upper
        A[t] = Gll - KPOS*mla[d]*mla[e];                                // la_cov
        P[t] = Gpp - KPOS*mpr[d]*mpr[e] + ((d == e) ? POS_ALPHA : 0.0); // pr_cov + aI
        M[t] = Glp - KPOS*mla[d]*mpr[e];                                // la_pr
    }
    __syncthreads();
    for (int k = 0; k < 9; k++) {
        if (t == 0) P[k*9+k] = sqrt(P[k*9+k]);
        __syncthreads();
        if (t > k && t < 9) P[t*9+k] /= P[k*9+k];
        __syncthreads();
        if (t < 81) {
            int i = t/9, jx = t - 9*(t/9);
            if (i > k && jx > k && jx <= i) P[i*9+jx] -= P[i*9+k]*P[jx*9+k];
        }
        __syncthreads();
    }
    if (t < 9) {
        double y[9];
        #pragma unroll
        for (int i = 0; i < 9; i++) {
            double sY = M[t*9 + i];
            #pragma unroll
            for (int m2 = 0; m2 < i; m2++) sY -= P[i*9+m2]*y[m2];
            y[i] = sY / P[i*9+i];
        }
        #pragma unroll
        for (int i = 0; i < 9; i++) Y[i*9 + t] = y[i];
    }
    __syncthreads();
    if (t < 81) {
        int d = t/9, e = t - 9*(t/9);
        double sY = 0.0;
        #pragma unroll
        for (int k = 0; k < 9; k++) sY += Y[k*9+d]*Y[k*9+e];
        A[t] = A[t] - sY + ((d == e) ? POS_ALPHA : 0.0);
    }
    __syncthreads();
    for (int k = 0; k < 9; k++) {
        if (t == 0) A[k*9+k] = sqrt(A[k*9+k]);
        __syncthreads();
        if (t > k && t < 9) A[t*9+k] /= A[k*9+k];
        __syncthreads();
        if (t < 81) {
            int i = t/9, jx = t - 9*(t/9);
            if (i > k && jx > k && jx <= i) A[i*9+jx] -= A[i*9+k]*A[jx*9+k];
        }
        __syncthreads();
    }
    if (t == 0) {
        double ld = 0.0;
        for (int k = 0; k < 9; k++) ld += log(A[k*9+k]);
        logdetArr[nc] = ld;
    }
}

// ---------------------------------------------------------------------------
// Kernel 4: final reduction of 4940 BCE partials + 76 logdets -> loss scalar.
// ---------------------------------------------------------------------------
__global__ __launch_bounds__(256) void k_final(
    const double2* __restrict__ part_bce,
    const double*  __restrict__ logdetArr,
    float* __restrict__ out)
{
    int t = threadIdx.x;
    double b = 0.0, v = 0.0, r = 0.0;
    for (int i = t; i < NBLK_BCE; i += 256) {
        double2 pv = part_bce[i];
        b += pv.x; v += pv.y;
    }
    for (int i = t; i < NC; i += 256) r += logdetArr[i];
    for (int off = 32; off > 0; off >>= 1) {
        b += __shfl_down(b, off);
        v += __shfl_down(v, off);
        r += __shfl_down(r, off);
    }
    __shared__ double sb[4], sv[4], sr[4];
    int wid = t >> 6, lane = t & 63;
    if (lane == 0) { sb[wid] = b; sv[wid] = v; sr[wid] = r; }
    __syncthreads();
    if (t == 0) {
        double bsum = sb[0]+sb[1]+sb[2]+sb[3];
        double vsum = sv[0]+sv[1]+sv[2]+sv[3];
        double rsum = sr[0]+sr[1]+sr[2]+sr[3];
        double bce  = bsum / (vsum + 1.0);
        out[0] = (float)(0.5*bce + 0.5*(rsum * (1.0/36.0)));  // LAMBDA=0.5; /(N*HALF_D)
    }
}

// ---------------------------------------------------------------------------
extern "C" void kernel_launch(void* const* d_in, const int* in_sizes, int n_in,
                              void* d_out, int out_size, void* d_ws, size_t ws_size,
                              hipStream_t stream)
{
    const float* logits = (const float*)d_in[0];
    const int*   labels = (const int*)d_in[1];
    float* out = (float*)d_out;

    float*   pla       = (float*)d_ws;                         // 76*16641 floats
    float*   ppr       = pla + (size_t)NC*PP;
    double*  part_gram = (double*)(ppr + (size_t)NC*PP);       // 76*16*190 doubles
    double2* part_bce  = (double2*)(part_gram + (size_t)NC*NSTRIP*190); // 4940 double2
    double*  logdetArr = (double*)(part_bce + NBLK_BCE);       // 76 doubles
    // total ws use ~12.05 MB; every slot read downstream is written -> no memset

    k_bce_pool<<<NBLK_BCE, 256, 0, stream>>>(logits, labels, pla, ppr, part_bce);
    k_gram<<<NC*NSTRIP, 576, 0, stream>>>(pla, ppr, part_gram);
    k_solve<<<NC, 192, 0, stream>>>(part_gram, logdetArr);
    k_final<<<1, 256, 0, stream>>>(part_bce, logdetArr, out);
}